// Round 4
// baseline (149.076 us; speedup 1.0000x reference)
//
#include <hip/hip_runtime.h>
#include <hip/hip_bf16.h>
#include <math.h>

// TopicRouter, two kernels:
//  A) router_logits: logits[B,8] = h @ gate_w^T + b. HBM-bound (96 MB of h).
//     Gate weights in 96 VGPRs/lane (loop-invariant). One wave per 4-row
//     quad per iteration: 12 float4 loads in flight (12 KB/wave), reduction
//     and store amortized over 4 rows. Software prefetch depth 1 in regs.
//     __launch_bounds__(256,2): 256-VGPR budget, static use ~249, no spill.
//  B) router_topk: per-thread top-2 + softmax over logits (1 MB), coalesced.

constexpr int D  = 768;
constexpr int E  = 8;
constexpr int D4 = D / 4;          // 192 float4 per row
constexpr int BLOCK  = 256;        // 4 waves
constexpr int GRID_A = 512;        // 2048 waves; 8192 quads -> 4 per wave

__device__ __forceinline__ float dot4acc(float4 a, float4 b, float acc) {
    acc = fmaf(a.x, b.x, acc);
    acc = fmaf(a.y, b.y, acc);
    acc = fmaf(a.z, b.z, acc);
    acc = fmaf(a.w, b.w, acc);
    return acc;
}
__device__ __forceinline__ float dot4(float4 a, float4 b) {
    return fmaf(a.x, b.x, fmaf(a.y, b.y, fmaf(a.z, b.z, a.w * b.w)));
}

// Reduce a[8] (per-expert partials) across 64 lanes.
// Returns: this lane's total for expert e = bitrev3(lane&7).
__device__ __forceinline__ float wave_reduce8(float a[8], int lane) {
    {   // xor 1: 8 -> 4 values
        const bool hi = lane & 1;
#pragma unroll
        for (int j = 0; j < 4; ++j) {
            float send = hi ? a[j] : a[j + 4];
            float recv = __shfl_xor(send, 1, 64);
            float keep = hi ? a[j + 4] : a[j];
            a[j] = keep + recv;
        }
    }
    {   // xor 2: 4 -> 2
        const bool hi = lane & 2;
#pragma unroll
        for (int j = 0; j < 2; ++j) {
            float send = hi ? a[j] : a[j + 2];
            float recv = __shfl_xor(send, 2, 64);
            float keep = hi ? a[j + 2] : a[j];
            a[j] = keep + recv;
        }
    }
    {   // xor 4: 2 -> 1
        const bool hi = lane & 4;
        float send = hi ? a[0] : a[1];
        float recv = __shfl_xor(send, 4, 64);
        float keep = hi ? a[1] : a[0];
        a[0] = keep + recv;
    }
    float v = a[0];
    v += __shfl_xor(v, 8, 64);
    v += __shfl_xor(v, 16, 64);
    v += __shfl_xor(v, 32, 64);
    return v;
}

// Load one quad (4 rows) of h: dst[r*3+c] = h4[row r of quad][c*64 + lane]
__device__ __forceinline__ void load_quad(float4 dst[12], const float4* __restrict__ h4,
                                          int quad, int lane) {
    const float4* hp = h4 + (size_t)quad * (4 * D4) + lane;
#pragma unroll
    for (int r = 0; r < 4; ++r)
#pragma unroll
        for (int c = 0; c < 3; ++c)
            dst[r * 3 + c] = hp[r * D4 + c * 64];
}

__global__ __launch_bounds__(BLOCK, 2)
void router_logits_kernel(const float* __restrict__ h,
                          const float* __restrict__ gate_w,
                          const float* __restrict__ gate_b,
                          float* __restrict__ out_logits,
                          int B) {
    const int tid    = threadIdx.x;
    const int lane   = tid & 63;
    const int wave   = tid >> 6;
    const int gwave  = blockIdx.x * (BLOCK / 64) + wave;
    const int nwaves = gridDim.x * (BLOCK / 64);

    const int l3 = lane & 7;
    const int e_lane = ((l3 & 1) << 2) | (l3 & 2) | ((l3 >> 2) & 1);  // bitrev3
    const float bias = gate_b[e_lane];

    // Loop-invariant gate slice for this lane: 24 float4 = 96 VGPRs.
    const float4* gw4 = (const float4*)gate_w;
    float4 greg[24];
#pragma unroll
    for (int e = 0; e < E; ++e)
#pragma unroll
        for (int c = 0; c < 3; ++c)
            greg[e * 3 + c] = gw4[e * D4 + c * 64 + lane];

    const float4* h4 = (const float4*)h;
    const int nquads = B >> 2;

    int q = gwave;
    if (q >= nquads) return;

    float4 cv[12];
    load_quad(cv, h4, q, lane);      // prime the pipeline

    while (true) {
        const int qn = q + nwaves;
        const bool more = (qn < nquads);   // wave-uniform branch

        float4 nv[12];
        if (more) load_quad(nv, h4, qn, lane);   // in flight during compute

        float acc[4][E];
#pragma unroll
        for (int r = 0; r < 4; ++r) {
#pragma unroll
            for (int e = 0; e < E; ++e) {
                // c = 0 initializes, c = 1,2 accumulate
                float a0 = dot4(cv[r * 3 + 0], greg[e * 3 + 0]);
                a0 = dot4acc(cv[r * 3 + 1], greg[e * 3 + 1], a0);
                a0 = dot4acc(cv[r * 3 + 2], greg[e * 3 + 2], a0);
                acc[r][e] = a0;
            }
        }

        float v0 = wave_reduce8(acc[0], lane) + bias;
        float v1 = wave_reduce8(acc[1], lane) + bias;
        float v2 = wave_reduce8(acc[2], lane) + bias;
        float v3 = wave_reduce8(acc[3], lane) + bias;

        // Lanes 0..31 write the quad's 32 logits as one 128 B chunk:
        // out[q*32 + (lane>>3)*8 + e_lane], value = v_{lane>>3}.
        float sel = (lane < 16) ? ((lane < 8) ? v0 : v1)
                                : ((lane < 24) ? v2 : v3);
        if (lane < 32) out_logits[(size_t)q * 32 + (lane & 24) + e_lane] = sel;

        if (!more) break;
#pragma unroll
        for (int i = 0; i < 12; ++i) cv[i] = nv[i];
        q = qn;
    }
}

__global__ __launch_bounds__(BLOCK)
void router_topk_kernel(const float* __restrict__ logits,
                        float* __restrict__ out_idx,
                        float* __restrict__ out_w,
                        int B) {
    const int t = blockIdx.x * BLOCK + threadIdx.x;
    if (t >= B) return;

    const float4* lp = (const float4*)(logits + (size_t)t * 8);
    float4 a = lp[0], b = lp[1];
    float l[8] = {a.x, a.y, a.z, a.w, b.x, b.y, b.z, b.w};

    // Stable top-2 (strict >): ties keep the lower expert index (lax.top_k).
    float v0 = l[0]; int i0 = 0;
    float v1 = -INFINITY; int i1 = -1;
#pragma unroll
    for (int e = 1; e < 8; ++e) {
        float x = l[e];
        bool gt0 = x > v0;
        bool gt1 = x > v1;
        float nv1 = gt0 ? v0 : (gt1 ? x : v1);
        int   ni1 = gt0 ? i0 : (gt1 ? e : i1);
        v1 = nv1; i1 = ni1;
        v0 = gt0 ? x : v0;
        i0 = gt0 ? e : i0;
    }
    float tt = expf(v1 - v0);
    float w0 = 1.0f / (1.0f + tt);
    float w1 = tt * w0;

    ((float2*)out_idx)[t] = make_float2((float)i0, (float)i1);
    ((float2*)out_w)[t]   = make_float2(w0, w1);
}

extern "C" void kernel_launch(void* const* d_in, const int* in_sizes, int n_in,
                              void* d_out, int out_size, void* d_ws, size_t ws_size,
                              hipStream_t stream) {
    const float* h      = (const float*)d_in[0];
    const float* gate_w = (const float*)d_in[1];
    const float* gate_b = (const float*)d_in[2];

    const int B = in_sizes[0] / D;   // 32768

    float* out        = (float*)d_out;
    float* out_idx    = out;                       // [B,2] indices as float
    float* out_w      = out + (size_t)B * 2;       // [B,2] weights
    float* out_logits = out + (size_t)B * 4;       // [B,8] logits

    router_logits_kernel<<<dim3(GRID_A), dim3(BLOCK), 0, stream>>>(
        h, gate_w, gate_b, out_logits, B);

    router_topk_kernel<<<dim3((B + BLOCK - 1) / BLOCK), dim3(BLOCK), 0, stream>>>(
        out_logits, out_idx, out_w, B);
}